// Round 1
// baseline (69.884 us; speedup 1.0000x reference)
//
#include <hip/hip_runtime.h>

#define NPTS 8192
#define THREADS 256
#define PPT 4                   // points per thread
#define PPB (THREADS * PPT)     // 1024 points per block
#define PBLKS (NPTS / PPB)      // 8 point-blocks
#define NCHUNK 16               // candidate chunks
#define CAND (NPTS / NCHUNK)    // 512 candidates per chunk

// Kernel 1: per (channel, direction, point-block, candidate-chunk) block,
// compute partial min |x - c| over the chunk's candidates, merge via atomicMin
// on uint bit patterns (valid ordering: all values are non-negative floats).
__global__ __launch_bounds__(THREADS) void chamfer_min_kernel(
    const float* __restrict__ pred, const float* __restrict__ target,
    unsigned int* __restrict__ ws)
{
    int b = blockIdx.x;
    const int ck  = b & (NCHUNK - 1); b >>= 4;
    const int pb  = b & (PBLKS - 1);  b >>= 3;
    const int dir = b & 1;            b >>= 1;
    const int ch  = b;                // 0..2

    const float* pts  = dir ? target : pred;   // dir=0: pred->target
    const float* cnds = dir ? pred   : target;

    __shared__ float s[CAND];
    const int t = threadIdx.x;
    #pragma unroll
    for (int k = t; k < CAND; k += THREADS)
        s[k] = cnds[(ck * CAND + k) * 3 + ch];

    float x[PPT], m[PPT];
    #pragma unroll
    for (int p = 0; p < PPT; ++p) {
        x[p] = pts[(pb * PPB + p * THREADS + t) * 3 + ch];
        m[p] = 3.0e38f;
    }
    __syncthreads();

    #pragma unroll 4
    for (int k = 0; k < CAND; ++k) {
        const float c = s[k];
        #pragma unroll
        for (int p = 0; p < PPT; ++p)
            m[p] = fminf(m[p], fabsf(x[p] - c));
    }

    unsigned int* w = ws + (ch * 2 + dir) * NPTS + pb * PPB;
    #pragma unroll
    for (int p = 0; p < PPT; ++p)
        atomicMin(&w[p * THREADS + t], __float_as_uint(m[p]));
}

// Kernel 2: reduce the 6*NPTS per-point mins -> sum of 6 means (scalar).
__global__ __launch_bounds__(THREADS) void chamfer_sum_kernel(
    const unsigned int* __restrict__ ws, float* __restrict__ out)
{
    const int t = threadIdx.x;
    float sum = 0.f;
    for (int i = t; i < 6 * NPTS; i += THREADS)
        sum += __uint_as_float(ws[i]);

    #pragma unroll
    for (int off = 32; off > 0; off >>= 1)
        sum += __shfl_down(sum, off, 64);

    __shared__ float wsum[THREADS / 64];
    const int wave = t >> 6;
    if ((t & 63) == 0) wsum[wave] = sum;
    __syncthreads();
    if (t == 0) {
        float tot = 0.f;
        #pragma unroll
        for (int w = 0; w < THREADS / 64; ++w) tot += wsum[w];
        out[0] = tot * (1.0f / NPTS);
    }
}

extern "C" void kernel_launch(void* const* d_in, const int* in_sizes, int n_in,
                              void* d_out, int out_size, void* d_ws, size_t ws_size,
                              hipStream_t stream) {
    const float* pred   = (const float*)d_in[0];
    const float* target = (const float*)d_in[1];
    float* out = (float*)d_out;
    unsigned int* ws = (unsigned int*)d_ws;

    // 0x7f7f7f7f == 3.39e38f: positive-float "infinity" sentinel for atomicMin.
    hipMemsetAsync(d_ws, 0x7f, (size_t)6 * NPTS * sizeof(unsigned int), stream);

    chamfer_min_kernel<<<3 * 2 * PBLKS * NCHUNK, THREADS, 0, stream>>>(pred, target, ws);
    chamfer_sum_kernel<<<1, THREADS, 0, stream>>>(ws, out);
}

// Round 2
// 27.242 us; speedup vs baseline: 2.5653x; 2.5653x over previous
//
#include <hip/hip_runtime.h>

#define NPTS 8192
#define THREADS 256
#define PPT 4                   // points per thread
#define PPB (THREADS * PPT)     // 1024 points per block
#define PBLKS (NPTS / PPB)      // 8 point-blocks
#define NCHUNK 16               // candidate chunks
#define CAND (NPTS / NCHUNK)    // 512 candidates per chunk
#define REDBLKS 48              // 6*NPTS / 1024 slices for stage-1 reduce

// Kernel 1: per (channel, direction, point-block, candidate-chunk) block,
// compute partial min |x - c| over the chunk's candidates, merge via atomicMin
// on uint bit patterns (valid ordering: all values are non-negative floats).
__global__ __launch_bounds__(THREADS) void chamfer_min_kernel(
    const float* __restrict__ pred, const float* __restrict__ target,
    unsigned int* __restrict__ ws)
{
    int b = blockIdx.x;
    const int ck  = b & (NCHUNK - 1); b >>= 4;
    const int pb  = b & (PBLKS - 1);  b >>= 3;
    const int dir = b & 1;            b >>= 1;
    const int ch  = b;                // 0..2

    const float* pts  = dir ? target : pred;   // dir=0: pred->target
    const float* cnds = dir ? pred   : target;

    __shared__ float s[CAND];
    const int t = threadIdx.x;
    #pragma unroll
    for (int k = t; k < CAND; k += THREADS)
        s[k] = cnds[(ck * CAND + k) * 3 + ch];

    float x[PPT], m[PPT];
    #pragma unroll
    for (int p = 0; p < PPT; ++p) {
        x[p] = pts[(pb * PPB + p * THREADS + t) * 3 + ch];
        m[p] = 3.0e38f;
    }
    __syncthreads();

    #pragma unroll 4
    for (int k = 0; k < CAND; ++k) {
        const float c = s[k];
        #pragma unroll
        for (int p = 0; p < PPT; ++p)
            m[p] = fminf(m[p], fabsf(x[p] - c));   // v_sub + v_min(abs-mod): 2 VALU/pair
    }

    unsigned int* w = ws + (ch * 2 + dir) * NPTS + pb * PPB;
    #pragma unroll
    for (int p = 0; p < PPT; ++p)
        atomicMin(&w[p * THREADS + t], __float_as_uint(m[p]));
}

// Stage 1 reduce: 48 blocks, each sums a contiguous 1024-float slice (float4
// coalesced) -> one partial per block.
__global__ __launch_bounds__(THREADS) void chamfer_red1_kernel(
    const float* __restrict__ ws, float* __restrict__ partials)
{
    const int t = threadIdx.x;
    const float4 v = ((const float4*)(ws + (size_t)blockIdx.x * 1024))[t];
    float sum = v.x + v.y + v.z + v.w;

    #pragma unroll
    for (int off = 32; off > 0; off >>= 1)
        sum += __shfl_down(sum, off, 64);

    __shared__ float wsum[THREADS / 64];
    if ((t & 63) == 0) wsum[t >> 6] = sum;
    __syncthreads();
    if (t == 0) {
        float tot = 0.f;
        #pragma unroll
        for (int w = 0; w < THREADS / 64; ++w) tot += wsum[w];
        partials[blockIdx.x] = tot;
    }
}

// Stage 2 reduce: one wave sums the 48 partials and scales by 1/NPTS.
__global__ __launch_bounds__(64) void chamfer_red2_kernel(
    const float* __restrict__ partials, float* __restrict__ out)
{
    const int t = threadIdx.x;
    float sum = (t < REDBLKS) ? partials[t] : 0.f;
    #pragma unroll
    for (int off = 32; off > 0; off >>= 1)
        sum += __shfl_down(sum, off, 64);
    if (t == 0) out[0] = sum * (1.0f / NPTS);
}

extern "C" void kernel_launch(void* const* d_in, const int* in_sizes, int n_in,
                              void* d_out, int out_size, void* d_ws, size_t ws_size,
                              hipStream_t stream) {
    const float* pred   = (const float*)d_in[0];
    const float* target = (const float*)d_in[1];
    float* out = (float*)d_out;
    unsigned int* ws = (unsigned int*)d_ws;
    float* partials = (float*)((char*)d_ws + (size_t)6 * NPTS * sizeof(float));

    // 0x7f7f7f7f == 3.39e38f: positive-float "infinity" sentinel for atomicMin.
    hipMemsetAsync(d_ws, 0x7f, (size_t)6 * NPTS * sizeof(unsigned int), stream);

    chamfer_min_kernel<<<3 * 2 * PBLKS * NCHUNK, THREADS, 0, stream>>>(pred, target, ws);
    chamfer_red1_kernel<<<REDBLKS, THREADS, 0, stream>>>((const float*)ws, partials);
    chamfer_red2_kernel<<<1, 64, 0, stream>>>(partials, out);
}